// Round 4
// baseline (195.875 us; speedup 1.0000x reference)
//
#include <hip/hip_runtime.h>

#define IN_CH 256
#define IMG_W 56
#define CH_FLOATS 3136            // 56*56 floats per channel image

typedef __attribute__((address_space(1))) const void GBuf;
typedef __attribute__((address_space(3))) void LBuf;
typedef float f4 __attribute__((ext_vector_type(4)));

// out[b,c0] = conv3x3(x[b,c0], w[2c0]) + conv3x3(x[b,c1], w[2c1+1])
// out[b,c1] = conv3x3(x[b,c1], w[2c1]) + conv3x3(x[b,c0], w[2c0+1]),  c1 = c0^4
//
// WAVE-AUTONOMOUS: no __syncthreads. Each wave stages its own 9-row x 2-ch
// window into a private 4KB LDS region (4x global_load_lds, linear), waits on
// its own vmcnt(0), computes 7 output rows x 56 cols x 2ch, NT-stores.
// Waves desynchronize -> up to 32 independent load streams per CU (convoy fix).
__global__ __launch_bounds__(256, 8) void dwconv_butterfly(
    const float* __restrict__ x, const float* __restrict__ wgt,
    float* __restrict__ out)
{
    __shared__ float lds[4 * 1024];   // 4 waves x (2ch x 512 floats) = 16384 B

    const int tid  = threadIdx.x;
    const int lane = tid & 63;
    const int w    = tid >> 6;        // wave 0..3
    const int p    = blockIdx.x;      // 0..127
    const int b    = blockIdx.y;      // 0..31
    const int band = blockIdx.z;      // 0..1
    const int c0   = ((p >> 2) << 3) | (p & 3);   // bit2 == 0
    const int c1   = c0 ^ 4;

    const float* x0 = x + ((size_t)b * IN_CH + c0) * CH_FLOATS;
    const float* x1 = x + ((size_t)b * IN_CH + c1) * CH_FLOATS;
    float* o0 = out + ((size_t)b * IN_CH + c0) * CH_FLOATS;
    float* o1 = out + ((size_t)b * IN_CH + c1) * CH_FLOATS;

    // wave w owns output rows obase..obase+6 ; input window rows obase-1..obase+7
    const int obase  = band * 28 + 7 * w;
    const int wstart = obase - 1;     // -1 only for (band0,w0); reaches 48 for (band1,w3)

    // ---- stage: 2 ch x 2 insts x 64 lanes x 16B = 4KB into private region ----
    // LDS slot for chunk k (=i*64+lane) is ALWAYS base+16k (linear); the global
    // source index is clamped per-lane into [0, CH_FLOATS-4] -- out-of-window
    // slots (g=-1 row, g=56 row, tail overrun) receive garbage that compute masks.
    float* const wlds = &lds[w * 1024];
#pragma unroll
    for (int ch = 0; ch < 2; ++ch) {
        const float* xc = ch ? x1 : x0;
#pragma unroll
        for (int i = 0; i < 2; ++i) {
            const int k  = i * 64 + lane;                 // chunk 0..127
            int fidx = wstart * IMG_W + 4 * k;            // float index in channel
            fidx = fidx < 0 ? 0 : (fidx > CH_FLOATS - 4 ? CH_FLOATS - 4 : fidx);
            __builtin_amdgcn_global_load_lds((GBuf*)(xc + fidx),
                (LBuf*)&wlds[ch * 512 + i * 256], 16, 0, 0);
        }
    }

    // ---- weights (block-uniform -> scalar loads, overlap staging latency) ----
    float wa[9], wb[9], wc[9], wd[9];
    {
        const float* pa = wgt + (size_t)(2 * c0) * 9;
        const float* pb = wgt + (size_t)(2 * c1 + 1) * 9;
        const float* pc = wgt + (size_t)(2 * c1) * 9;
        const float* pd = wgt + (size_t)(2 * c0 + 1) * 9;
#pragma unroll
        for (int i = 0; i < 9; ++i) {
            wa[i] = pa[i]; wb[i] = pb[i]; wc[i] = pc[i]; wd[i] = pd[i];
        }
    }

    // wait for THIS WAVE's staging only -- no barrier, waves stay desynchronized
    asm volatile("s_waitcnt vmcnt(0)" ::: "memory");
    __builtin_amdgcn_sched_barrier(0);

    // ---- compute: 98 units (7 rows x 14 col-strips), <=2 per lane ----
#pragma unroll
    for (int pass = 0; pass < 2; ++pass) {
        const int u = lane + 64 * pass;
        if (u < 98) {
            const int r  = u / 14;                // 0..6 (local out row)
            const int s  = u - r * 14;            // 0..13 (4-col strip)
            const int w0 = 4 * s;
            const bool has_l = (s > 0);
            const bool has_r = (s < 13);
            const int  col_l = has_l ? w0 - 1 : 0;
            const int  col_r = has_r ? w0 + 4 : 55;

            // window row l = r+kh ; invalid rows: l==0 for (band0,wave0) [g=-1],
            // l==8 for (band1,wave3) [g=56]
            float W[3][12];   // [kh][ch*6 + c]; c=0: col w0-1, 1..4: w0.., 5: w0+4
#pragma unroll
            for (int kh = 0; kh < 3; ++kh) {
                const int  l  = r + kh;           // 0..8
                const bool zr = (band == 0 && w == 0 && l == 0) ||
                                (band == 1 && w == 3 && l == 8);
                const float* p0 = &wlds[l * IMG_W + w0];      // 16B aligned
                const float* p1 = p0 + 512;
                const f4 a0 = *(const f4*)p0;
                const f4 a1 = *(const f4*)p1;
                const float l0 = wlds[l * IMG_W + col_l];
                const float r0 = wlds[l * IMG_W + col_r];
                const float l1 = wlds[512 + l * IMG_W + col_l];
                const float r1 = wlds[512 + l * IMG_W + col_r];
                W[kh][0]  = (zr || !has_l) ? 0.f : l0;
                W[kh][1]  = zr ? 0.f : a0.x;
                W[kh][2]  = zr ? 0.f : a0.y;
                W[kh][3]  = zr ? 0.f : a0.z;
                W[kh][4]  = zr ? 0.f : a0.w;
                W[kh][5]  = (zr || !has_r) ? 0.f : r0;
                W[kh][6]  = (zr || !has_l) ? 0.f : l1;
                W[kh][7]  = zr ? 0.f : a1.x;
                W[kh][8]  = zr ? 0.f : a1.y;
                W[kh][9]  = zr ? 0.f : a1.z;
                W[kh][10] = zr ? 0.f : a1.w;
                W[kh][11] = (zr || !has_r) ? 0.f : r1;
            }

            float acc[8];     // [ch*4 + i]
#pragma unroll
            for (int i = 0; i < 8; ++i) acc[i] = 0.f;
#pragma unroll
            for (int kh = 0; kh < 3; ++kh) {
#pragma unroll
                for (int kw = 0; kw < 3; ++kw) {
                    const float fa = wa[kh * 3 + kw], fb = wb[kh * 3 + kw];
                    const float fc = wc[kh * 3 + kw], fd = wd[kh * 3 + kw];
#pragma unroll
                    for (int i = 0; i < 4; ++i) {
                        const float u0 = W[kh][i + kw];
                        const float u1 = W[kh][6 + i + kw];
                        acc[i]     += u0 * fa + u1 * fb;
                        acc[4 + i] += u1 * fc + u0 * fd;
                    }
                }
            }

            const int orow = obase + r;
            f4 v0; v0.x = acc[0]; v0.y = acc[1]; v0.z = acc[2]; v0.w = acc[3];
            f4 v1; v1.x = acc[4]; v1.y = acc[5]; v1.z = acc[6]; v1.w = acc[7];
            __builtin_nontemporal_store(v0, (f4*)(o0 + orow * IMG_W + w0));
            __builtin_nontemporal_store(v1, (f4*)(o1 + orow * IMG_W + w0));
        }
    }
}

extern "C" void kernel_launch(void* const* d_in, const int* in_sizes, int n_in,
                              void* d_out, int out_size, void* d_ws, size_t ws_size,
                              hipStream_t stream) {
    const float* x = (const float*)d_in[0];   // (32, 256, 56, 56) fp32
    const float* w = (const float*)d_in[1];   // (512, 1, 3, 3)   fp32
    float* out = (float*)d_out;               // (32, 256, 56, 56) fp32

    dim3 grid(IN_CH / 2, 32, 2);  // 128 pairs x 32 batch x 2 bands
    dim3 block(256);
    dwconv_butterfly<<<grid, block, 0, stream>>>(x, w, out);
}

// Round 6
// 195.202 us; speedup vs baseline: 1.0035x; 1.0035x over previous
//
#include <hip/hip_runtime.h>

#define IN_CH 256
#define IMG_W 56
typedef float f4 __attribute__((ext_vector_type(4)));

// out[b,c0] = conv3x3(x[b,c0], w[2c0]) + conv3x3(x[b,c1], w[2c1+1])
// out[b,c1] = conv3x3(x[b,c1], w[2c1]) + conv3x3(x[b,c0], w[2c0+1]),  c1 = c0^4
//
// PURE STREAM: no LDS, no barriers, no waitcnt stops. One block per
// (pair,batch) so weights are block-uniform (SGPR s_loads). Each active
// thread owns a 2-row x 4-col strip of both channels: 24 independent global
// loads (L1/L2 absorb the 2x row overlap), 288 FMAs, 4 float4 stores.
// Blocks have zero LDS -> no allocation serialization; waves never hard-stop.
__global__ __launch_bounds__(448, 5) void dwconv_butterfly(
    const float* __restrict__ x, const float* __restrict__ wgt,
    float* __restrict__ out)
{
    const int tid = threadIdx.x;          // 0..447 (7 waves)
    const int pb  = blockIdx.x;           // 0..4095 = 128 pairs x 32 batches
    const int p   = pb & 127;
    const int b   = pb >> 7;
    const int c0  = ((p >> 2) << 3) | (p & 3);   // bit2 == 0
    const int c1  = c0 ^ 4;

    const size_t chan = (size_t)IMG_W * IMG_W;
    const float* x0 = x + ((size_t)b * IN_CH + c0) * chan;
    const float* x1 = x + ((size_t)b * IN_CH + c1) * chan;
    float* o0 = out + ((size_t)b * IN_CH + c0) * chan;
    float* o1 = out + ((size_t)b * IN_CH + c1) * chan;

    // weights: block-uniform pointers -> scalar loads into SGPRs
    const float* pwa = wgt + (size_t)(2 * c0) * 9;      // out c0 <- x c0
    const float* pwb = wgt + (size_t)(2 * c1 + 1) * 9;  // out c0 <- x c1
    const float* pwc = wgt + (size_t)(2 * c1) * 9;      // out c1 <- x c1
    const float* pwd = wgt + (size_t)(2 * c0 + 1) * 9;  // out c1 <- x c0
    float wa[9], wb[9], wc[9], wd[9];
#pragma unroll
    for (int i = 0; i < 9; ++i) {
        wa[i] = pwa[i]; wb[i] = pwb[i]; wc[i] = pwc[i]; wd[i] = pwd[i];
    }

    if (tid >= 392) return;               // 392 units = 28 row-pairs x 14 strips
    const int s  = tid % 14;              // 4-col strip
    const int rp = tid / 14;              // 0..27 row-pair (out rows 2rp, 2rp+1)
    const int w0 = 4 * s;
    const bool has_l = (s > 0), has_r = (s < 13);
    const int  col_l = has_l ? w0 - 1 : 0;       // clamped, value masked
    const int  col_r = has_r ? w0 + 4 : IMG_W - 1;

    // taps k=0..3 -> input row 2rp-1+k ; rows -1 and 56 are masked to zero
    f4    va[4], vb[4];
    float la[4], ra[4], lb[4], rb[4];
    bool  rv[4];
#pragma unroll
    for (int k = 0; k < 4; ++k) {
        const int ir  = 2 * rp - 1 + k;
        rv[k] = (unsigned)ir < 56u;
        const int irc = ir < 0 ? 0 : (ir > 55 ? 55 : ir);
        const float* r0 = x0 + irc * IMG_W;
        const float* r1 = x1 + irc * IMG_W;
        va[k] = *(const f4*)(r0 + w0);    // 16B aligned
        vb[k] = *(const f4*)(r1 + w0);
        la[k] = r0[col_l];
        ra[k] = r0[col_r];
        lb[k] = r1[col_l];
        rb[k] = r1[col_r];
    }

    float acc[2][8];                      // [out row j][ch*4 + i]
#pragma unroll
    for (int j = 0; j < 2; ++j)
#pragma unroll
        for (int i = 0; i < 8; ++i) acc[j][i] = 0.f;

#pragma unroll
    for (int k = 0; k < 4; ++k) {
        const bool z = !rv[k];
        float W0[6], W1[6];               // 6-col window per channel for tap k
        W0[0] = (z || !has_l) ? 0.f : la[k];
        W0[1] = z ? 0.f : va[k].x;  W0[2] = z ? 0.f : va[k].y;
        W0[3] = z ? 0.f : va[k].z;  W0[4] = z ? 0.f : va[k].w;
        W0[5] = (z || !has_r) ? 0.f : ra[k];
        W1[0] = (z || !has_l) ? 0.f : lb[k];
        W1[1] = z ? 0.f : vb[k].x;  W1[2] = z ? 0.f : vb[k].y;
        W1[3] = z ? 0.f : vb[k].z;  W1[4] = z ? 0.f : vb[k].w;
        W1[5] = (z || !has_r) ? 0.f : rb[k];
        // tap k serves output row j with kernel row kh = k - j (0..2)
#pragma unroll
        for (int j = 0; j < 2; ++j) {
            const int kh = k - j;
            if (kh < 0 || kh > 2) continue;
#pragma unroll
            for (int kw = 0; kw < 3; ++kw) {
                const float fa = wa[kh * 3 + kw], fb = wb[kh * 3 + kw];
                const float fc = wc[kh * 3 + kw], fd = wd[kh * 3 + kw];
#pragma unroll
                for (int i = 0; i < 4; ++i) {
                    const float u0 = W0[i + kw];
                    const float u1 = W1[i + kw];
                    acc[j][i]     += u0 * fa + u1 * fb;
                    acc[j][4 + i] += u1 * fc + u0 * fd;
                }
            }
        }
    }

#pragma unroll
    for (int j = 0; j < 2; ++j) {
        const int orow = 2 * rp + j;
        f4 v0; v0.x = acc[j][0]; v0.y = acc[j][1]; v0.z = acc[j][2]; v0.w = acc[j][3];
        f4 v1; v1.x = acc[j][4]; v1.y = acc[j][5]; v1.z = acc[j][6]; v1.w = acc[j][7];
        *(f4*)(o0 + orow * IMG_W + w0) = v0;
        *(f4*)(o1 + orow * IMG_W + w0) = v1;
    }
}

extern "C" void kernel_launch(void* const* d_in, const int* in_sizes, int n_in,
                              void* d_out, int out_size, void* d_ws, size_t ws_size,
                              hipStream_t stream) {
    const float* x = (const float*)d_in[0];   // (32, 256, 56, 56) fp32
    const float* w = (const float*)d_in[1];   // (512, 1, 3, 3)   fp32
    float* out = (float*)d_out;               // (32, 256, 56, 56) fp32

    dim3 grid(128 * 32);    // one block per (pair, batch)
    dim3 block(448);        // 7 waves; 392 active compute lanes
    dwconv_butterfly<<<grid, block, 0, stream>>>(x, w, out);
}